// Round 4
// baseline (315.641 us; speedup 1.0000x reference)
//
#include <hip/hip_runtime.h>
#include <hip/hip_fp16.h>

typedef __attribute__((ext_vector_type(4)))  int   i32x4;
typedef __attribute__((ext_vector_type(16))) int   i32x16;

#define ALPHA 32
#define BM 256
#define BN 128
#define BK 64

// Tiled int8 workspace layout (matches GEMM LDS exactly):
//   addr(row, k) = (row>>5)*(32*K) + (k>>4)*512 + (row&31)*16 + (k&15)
// i.e. panels of 32 rows; within a panel, 16B k-chunks are row-interleaved.

// ---------------- kernel A: top-32 of |act_max| + keep-bitmask ----------------
__global__ __launch_bounds__(256) void topk_kernel(const float* __restrict__ act_max,
                                                   int* __restrict__ idx_out,
                                                   unsigned* __restrict__ tbits,
                                                   int K) {
  __shared__ float v[4096];
  __shared__ float rv[4];
  __shared__ int   ri[4];
  __shared__ unsigned bits[128];
  const int t = threadIdx.x;
  for (int i = t; i < K; i += 256) v[i] = fabsf(act_max[i]);
  for (int i = t; i < K / 32; i += 256) bits[i] = 0xFFFFFFFFu;
  __syncthreads();
  for (int sel = 0; sel < ALPHA; ++sel) {
    float bv = -1.f; int bi = 0;
    for (int i = t; i < K; i += 256) {
      float x = v[i];
      if (x > bv) { bv = x; bi = i; }   // ascending scan: strict > keeps lowest index
    }
    for (int m = 1; m < 64; m <<= 1) {
      float ov = __shfl_xor(bv, m);
      int   oi = __shfl_xor(bi, m);
      if (ov > bv || (ov == bv && oi < bi)) { bv = ov; bi = oi; }
    }
    if ((t & 63) == 0) { rv[t >> 6] = bv; ri[t >> 6] = bi; }
    __syncthreads();
    if (t == 0) {
      for (int u = 1; u < 4; ++u)
        if (rv[u] > bv || (rv[u] == bv && ri[u] < bi)) { bv = rv[u]; bi = ri[u]; }
      idx_out[sel] = bi;
      v[bi] = -2.f;                         // remove from candidates
      bits[bi >> 5] &= ~(1u << (bi & 31));  // t = 0 at outlier
    }
    __syncthreads();
  }
  for (int i = t; i < K / 32; i += 256) tbits[i] = bits[i];
}

// ------------- kernel B: fused W+X panel quantization + gather -------------
// One block = one 32-row panel (1024 threads). Groups of 8 rows held in regs:
// coalesced reads -> per-row max (shuffle) -> quantize from regs -> swizzled
// LDS tile -> tiled-layout stores as 128B-contiguous segments.
__global__ __launch_bounds__(1024) void quant_panel_kernel(
    const float* __restrict__ srcW, const float* __restrict__ srcX,
    const unsigned* __restrict__ tbits, const int* __restrict__ idx,
    signed char* __restrict__ wq, signed char* __restrict__ xq,
    _Float16* __restrict__ wmax, _Float16* __restrict__ xmax,
    float* __restrict__ wuf, float* __restrict__ xuf,
    int npw, int K, int N, int M) {
  const int t = threadIdx.x;
  const int b = blockIdx.x;
  const float* src; signed char* q; _Float16* smax; float* unq; int r0, R;
  if (b < npw) { src = srcW; q = wq; smax = wmax; unq = wuf; r0 = b * 32; R = N; }
  else         { src = srcX; q = xq; smax = xmax; unq = xuf; r0 = (b - npw) * 32; R = M; }
  __shared__ unsigned bits[128];
  __shared__ float wred[8][16];
  __shared__ float scs[8];
  __shared__ signed char qt[8 * 4096];   // 32 KB, swizzled chunk tile
  const int lane = t & 63, w = t >> 6;
  for (int i = t; i < K / 32; i += 1024) bits[i] = tbits[i];
  __syncthreads();
  const int k0 = t * 4;                       // this thread's 4 columns (all rows)
  const unsigned bw = bits[k0 >> 5] >> (k0 & 31);
  const bool m0 = bw & 1u, m1 = bw & 2u, m2 = bw & 4u, m3 = bw & 8u;
  const size_t pbase = (size_t)r0 * K;
  for (int g = 0; g < 4; ++g) {
    float4 v[8];
#pragma unroll
    for (int i = 0; i < 8; ++i) {             // coalesced: wave reads 1KB contiguous
      float4 x = ((const float4*)(src + (size_t)(r0 + g * 8 + i) * K))[t];
      if (!m0) x.x = 0.f; if (!m1) x.y = 0.f; if (!m2) x.z = 0.f; if (!m3) x.w = 0.f;
      v[i] = x;
      float am = fmaxf(fmaxf(fabsf(x.x), fabsf(x.y)), fmaxf(fabsf(x.z), fabsf(x.w)));
#pragma unroll
      for (int m = 1; m < 64; m <<= 1) am = fmaxf(am, __shfl_xor(am, m));
      if (lane == 0) wred[i][w] = am;
    }
    __syncthreads();
    if (t < 8) {
      float am = wred[t][0];
#pragma unroll
      for (int u = 1; u < 16; ++u) am = fmaxf(am, wred[t][u]);
      _Float16 sh = (_Float16)(am / 127.0f);  // RTN to fp16, like astype(float16)
      scs[t] = (float)sh;
      smax[r0 + g * 8 + t] = sh;
    }
    __syncthreads();
    const int cc = t >> 2, sub = (t & 3) * 4;
#pragma unroll
    for (int i = 0; i < 8; ++i) {
      const float s = scs[i];
      char4 c;
      c.x = (signed char)(v[i].x / s);   // fp32 divide + trunc = astype(int8)
      c.y = (signed char)(v[i].y / s);
      c.z = (signed char)(v[i].z / s);
      c.w = (signed char)(v[i].w / s);
      *(char4*)(qt + cc * 128 + ((i ^ (cc & 7)) << 4) + sub) = c;   // swizzled write
    }
    __syncthreads();
#pragma unroll
    for (int i = 0; i < 2; ++i) {
      const int l = i * 1024 + t;
      const int c2 = l >> 3, rl = l & 7;
      int4 d = *(const int4*)(qt + c2 * 128 + ((rl ^ (c2 & 7)) << 4));
      *(int4*)(q + pbase + (size_t)c2 * 512 + (size_t)((g * 8 + rl) << 4)) = d;
    }
    __syncthreads();
  }
  { // outlier gather: 32 idx x 32 rows
    const int j = t >> 5, rl = t & 31;
    unq[(size_t)j * R + r0 + rl] = src[(size_t)(r0 + rl) * K + idx[j]];
  }
}

// ---------------- kernel D: i8 GEMM, 2-phase pipelined, fused epilogue ----------------
__device__ __forceinline__ void gld_lds16(const signed char* g, signed char* l) {
  __builtin_amdgcn_global_load_lds(
      (const __attribute__((address_space(1))) void*)g,
      (__attribute__((address_space(3))) void*)l, 16, 0, 0);
}

__global__ __launch_bounds__(256, 2) void gemm_kernel(
    const signed char* __restrict__ xq, const signed char* __restrict__ wq,
    const _Float16* __restrict__ xmax, const _Float16* __restrict__ wmax,
    const float* __restrict__ xuf,   // [ALPHA][M]
    const float* __restrict__ wuf,   // [ALPHA][N]
    const float* __restrict__ bias,  // [N]
    float* __restrict__ out, int M, int N, int K) {
  __shared__ union {
    struct { signed char A[2][BM * BK]; signed char B[2][BN * BK]; } g;  // 48 KB dbuf
    struct { float xu[ALPHA * BM]; float wu[ALPHA * BN]; } e;            // 48 KB
  } sm;
  __shared__ _Float16 xmh[BM];
  __shared__ _Float16 wmh[BN];
  __shared__ float    bl[BN];

  const int t = threadIdx.x;
  // XCD-aware swizzle: 1024 blocks, 8 XCDs -> each XCD owns 4 consecutive bx.
  const int bid = blockIdx.y * gridDim.x + blockIdx.x;
  const int xcd = bid & 7, loc = bid >> 3;
  const int bxi = xcd * 4 + (loc & 3);
  const int byi = loc >> 2;
  const int bm0 = byi * BM;
  const int bn0 = bxi * BN;
  const int lane = t & 63, w = t >> 6;
  const int wm = w >> 1, wn = w & 1;       // 2x2 waves, wave tile 128x64
  const int hi = lane >> 5, l31 = lane & 31;

  i32x16 acc[4][2] = {};

  // staging: issue i copies 4KB contiguous global (2 panels x 4 chunk-cols)
  // to LDS linearly at slot t*16. A: 4 issues (16KB), B: 2 issues (8KB).
  const int tp = t >> 7;                  // panel parity within an issue
  const int to = (t & 127) * 16;
  const signed char* aS = xq + (size_t)bm0 * K + (size_t)tp * 32 * K + to;
  const signed char* bS = wq + (size_t)bn0 * K + (size_t)tp * 32 * K + to;
  signed char* const aD = &sm.g.A[0][0] + t * 16;
  signed char* const bD = &sm.g.B[0][0] + t * 16;
  const size_t PSTR = (size_t)64 * K;     // 2-panel stride

  auto STAGE = [&](int buf, int kt) {
    const size_t ko = (size_t)kt * 2048;  // (kt*64)>>4 * 512
#pragma unroll
    for (int i = 0; i < 4; ++i)
      gld_lds16(aS + (size_t)i * PSTR + ko, aD + buf * (BM * BK) + i * 4096);
#pragma unroll
    for (int i = 0; i < 2; ++i)
      gld_lds16(bS + (size_t)i * PSTR + ko, bD + buf * (BN * BK) + i * 4096);
  };

  STAGE(0, 0);
  const int NT = K >> 6;   // 64
  const signed char* const aR0 = &sm.g.A[0][0] + (wm * 4) * 2048 + 16 * lane;
  const signed char* const bR0 = &sm.g.B[0][0] + (wn * 2) * 2048 + 16 * lane;

  for (int kt = 0; kt < NT; ++kt) {
    const int cur = kt & 1;
    // staging for THIS tile was issued last iter; it overlapped that iter's MFMAs.
    asm volatile("s_waitcnt vmcnt(0)" ::: "memory");
    asm volatile("s_barrier" ::: "memory");
    const signed char* aRd = aR0 + cur * (BM * BK);
    const signed char* bRd = bR0 + cur * (BN * BK);
    i32x4 af[2][4], bf[2][2];
#pragma unroll
    for (int ks = 0; ks < 2; ++ks) {
#pragma unroll
      for (int mi = 0; mi < 4; ++mi) af[ks][mi] = *(const i32x4*)(aRd + mi * 2048 + ks * 1024);
#pragma unroll
      for (int ni = 0; ni < 2; ++ni) bf[ks][ni] = *(const i32x4*)(bRd + ni * 2048 + ks * 1024);
    }
    if (kt + 1 < NT) STAGE(cur ^ 1, kt + 1);   // prefetch flies under the MFMAs
    __builtin_amdgcn_s_setprio(1);
#pragma unroll
    for (int ks = 0; ks < 2; ++ks)
#pragma unroll
      for (int mi = 0; mi < 4; ++mi)
#pragma unroll
        for (int ni = 0; ni < 2; ++ni)
          acc[mi][ni] = __builtin_amdgcn_mfma_i32_32x32x32_i8(af[ks][mi], bf[ks][ni], acc[mi][ni], 0, 0, 0);
    __builtin_amdgcn_s_setprio(0);
  }

  __syncthreads();
  // ---- epilogue staging (reuses GEMM LDS) ----
  {
    const float4* xs = (const float4*)xuf;
    float4* xl = (float4*)sm.e.xu;
#pragma unroll
    for (int i = 0; i < 8; ++i) {   // 2048 float4
      int p = i * 256 + t;
      int j = p >> 6, r4 = p & 63;
      xl[p] = xs[(size_t)j * (M >> 2) + (bm0 >> 2) + r4];
    }
    const float4* wsrc = (const float4*)wuf;
    float4* wl = (float4*)sm.e.wu;
#pragma unroll
    for (int i = 0; i < 4; ++i) {   // 1024 float4
      int p = i * 256 + t;
      int j = p >> 5, r4 = p & 31;
      wl[p] = wsrc[(size_t)j * (N >> 2) + (bn0 >> 2) + r4];
    }
    if (t < BM / 2) ((unsigned*)xmh)[t] = ((const unsigned*)(xmax + bm0))[t];
    if (t < BN / 2) ((unsigned*)wmh)[t] = ((const unsigned*)(wmax + bn0))[t];
    if (t < BN / 4) ((float4*)bl)[t] = ((const float4*)(bias + bn0))[t];
  }
  __syncthreads();

  const int c0 = wn * 64 + l31;   // column (within tile) for ni=0; ni=1 is +32
  const _Float16 wh0 = wmh[c0], wh1 = wmh[c0 + 32];
  const float bv0 = bl[c0], bv1 = bl[c0 + 32];
  const float* xul = sm.e.xu;     // [ALPHA][BM]
  const float* wul = sm.e.wu;     // [ALPHA][BN]

#pragma unroll
  for (int mi = 0; mi < 4; ++mi) {
    const int rbase = wm * 128 + mi * 32 + 4 * hi;   // + (r&3) + 8*(r>>2)
    float f0[16], f1[16];
#pragma unroll
    for (int r = 0; r < 16; ++r) {
      int row = rbase + (r & 3) + 8 * (r >> 2);
      _Float16 xh = xmh[row];
      float mx0 = (float)(_Float16)(xh * wh0);   // fp16 multiply (subnormal-correct) like ref
      float mx1 = (float)(_Float16)(xh * wh1);
      f0[r] = (float)acc[mi][0][r] * mx0 + bv0;
      f1[r] = (float)acc[mi][1][r] * mx1 + bv1;
    }
#pragma unroll 4
    for (int j = 0; j < ALPHA; ++j) {            // rank-32 fp32 outlier update
      const float4* xrow4 = (const float4*)(xul + j * BM + rbase);
      float wv0 = wul[j * BN + c0];
      float wv1 = wul[j * BN + c0 + 32];
#pragma unroll
      for (int gq = 0; gq < 4; ++gq) {
        float4 xv = xrow4[gq * 2];               // rows rbase + 8*gq .. +3
        f0[gq * 4 + 0] += xv.x * wv0;  f1[gq * 4 + 0] += xv.x * wv1;
        f0[gq * 4 + 1] += xv.y * wv0;  f1[gq * 4 + 1] += xv.y * wv1;
        f0[gq * 4 + 2] += xv.z * wv0;  f1[gq * 4 + 2] += xv.z * wv1;
        f0[gq * 4 + 3] += xv.w * wv0;  f1[gq * 4 + 3] += xv.w * wv1;
      }
    }
#pragma unroll
    for (int r = 0; r < 16; ++r) {
      int row = bm0 + rbase + (r & 3) + 8 * (r >> 2);
      size_t o = (size_t)row * N + bn0;
      out[o + c0] = f0[r];
      out[o + c0 + 32] = f1[r];
    }
  }
}

// ---------------- launch ----------------
extern "C" void kernel_launch(void* const* d_in, const int* in_sizes, int n_in,
                              void* d_out, int out_size, void* d_ws, size_t ws_size,
                              hipStream_t stream) {
  const float* x       = (const float*)d_in[0];
  const float* W       = (const float*)d_in[1];
  const float* bias    = (const float*)d_in[2];
  const float* act_max = (const float*)d_in[3];
  const int K = in_sizes[3];            // 4096
  const int N = in_sizes[1] / K;        // 4096
  const int M = in_sizes[0] / K;        // 8192
  float* out = (float*)d_out;

  char* ws = (char*)d_ws;
  size_t off = 0;
  auto take = [&](size_t b) { char* p = ws + off; off += (b + 255) & ~(size_t)255; return p; };
  signed char* wq  = (signed char*)take((size_t)N * K);
  signed char* xq  = (signed char*)take((size_t)M * K);
  _Float16* wmax   = (_Float16*)take((size_t)N * 2);
  _Float16* xmax   = (_Float16*)take((size_t)M * 2);
  float* wuf       = (float*)take((size_t)ALPHA * N * 4);
  float* xuf       = (float*)take((size_t)ALPHA * M * 4);
  int* idx         = (int*)take(ALPHA * 4);
  unsigned* tbits  = (unsigned*)take((size_t)(K / 32) * 4);

  const int npw = N / 32, npx = M / 32;
  topk_kernel<<<1, 256, 0, stream>>>(act_max, idx, tbits, K);
  quant_panel_kernel<<<npw + npx, 1024, 0, stream>>>(W, x, tbits, idx, wq, xq,
                                                     wmax, xmax, wuf, xuf, npw, K, N, M);
  dim3 grid(N / BN, M / BM);
  gemm_kernel<<<grid, 256, 0, stream>>>(xq, wq, xmax, wmax, xuf, wuf, bias, out, M, N, K);
}

// Round 5
// 276.840 us; speedup vs baseline: 1.1402x; 1.1402x over previous
//
#include <hip/hip_runtime.h>
#include <hip/hip_fp16.h>

typedef __attribute__((ext_vector_type(4)))  int   i32x4;
typedef __attribute__((ext_vector_type(16))) int   i32x16;

#define ALPHA 32
#define BM 256
#define BN 128
#define BK 64

// Tiled int8 workspace layout (matches GEMM LDS exactly):
//   addr(row, k) = (row>>5)*(32*K) + (k>>4)*512 + (row&31)*16 + (k&15)

// ---------------- kernel A: top-32 of |act_max| + keep-bitmask ----------------
__global__ __launch_bounds__(256) void topk_kernel(const float* __restrict__ act_max,
                                                   int* __restrict__ idx_out,
                                                   unsigned* __restrict__ tbits,
                                                   int K) {
  __shared__ float v[4096];
  __shared__ float rv[4];
  __shared__ int   ri[4];
  __shared__ unsigned bits[128];
  const int t = threadIdx.x;
  for (int i = t; i < K; i += 256) v[i] = fabsf(act_max[i]);
  for (int i = t; i < K / 32; i += 256) bits[i] = 0xFFFFFFFFu;
  __syncthreads();
  for (int sel = 0; sel < ALPHA; ++sel) {
    float bv = -1.f; int bi = 0;
    for (int i = t; i < K; i += 256) {
      float x = v[i];
      if (x > bv) { bv = x; bi = i; }
    }
    for (int m = 1; m < 64; m <<= 1) {
      float ov = __shfl_xor(bv, m);
      int   oi = __shfl_xor(bi, m);
      if (ov > bv || (ov == bv && oi < bi)) { bv = ov; bi = oi; }
    }
    if ((t & 63) == 0) { rv[t >> 6] = bv; ri[t >> 6] = bi; }
    __syncthreads();
    if (t == 0) {
      for (int u = 1; u < 4; ++u)
        if (rv[u] > bv || (rv[u] == bv && ri[u] < bi)) { bv = rv[u]; bi = ri[u]; }
      idx_out[sel] = bi;
      v[bi] = -2.f;
      bits[bi >> 5] &= ~(1u << (bi & 31));
    }
    __syncthreads();
  }
  for (int i = t; i < K / 32; i += 256) tbits[i] = bits[i];
}

// ------------- kernel B: 8-rows-per-block quantization + gather -------------
// 256 threads = 4 waves; wave w owns rows w and w+4. Coalesced 1KB reads,
// per-wave max (6 shuffles), quantize in-reg, bounce via XOR-swizzled 32KB
// LDS tile, store tiled layout as 128B-contiguous segments.
__global__ __launch_bounds__(256) void quant8_kernel(
    const float* __restrict__ srcW, const float* __restrict__ srcX,
    const unsigned* __restrict__ tbits, const int* __restrict__ idxg,
    signed char* __restrict__ wq, signed char* __restrict__ xq,
    _Float16* __restrict__ wmax, _Float16* __restrict__ xmax,
    float* __restrict__ wuf, float* __restrict__ xuf,
    int nbw, int K, int N, int M) {
  const int t = threadIdx.x, lane = t & 63, w = t >> 6;
  const int b = blockIdx.x;
  const float* src; signed char* q; _Float16* smax; float* unq; int r0, R;
  if (b < nbw) { src = srcW; q = wq; smax = wmax; unq = wuf; r0 = b * 8; R = N; }
  else         { src = srcX; q = xq; smax = xmax; unq = xuf; r0 = (b - nbw) * 8; R = M; }
  __shared__ unsigned bits[128];
  __shared__ signed char qt[8 * 4096];   // [row][swizzled chunk]
  for (int i = t; i < 128; i += 256) bits[i] = tbits[i];
  __syncthreads();
  const int shft = (lane & 7) * 4;
#pragma unroll
  for (int g = 0; g < 2; ++g) {
    const int rl = w + 4 * g;            // local row 0..7
    const float4* srow = (const float4*)(src + (size_t)(r0 + rl) * K);
    float4 v[16];
    float am = 0.f;
#pragma unroll
    for (int j = 0; j < 16; ++j) {       // wave reads 1KB contiguous per instr
      float4 x = srow[j * 64 + lane];
      unsigned b4 = bits[j * 8 + (lane >> 3)] >> shft;
      if (!(b4 & 1u)) x.x = 0.f;
      if (!(b4 & 2u)) x.y = 0.f;
      if (!(b4 & 4u)) x.z = 0.f;
      if (!(b4 & 8u)) x.w = 0.f;
      v[j] = x;
      am = fmaxf(am, fmaxf(fmaxf(fabsf(x.x), fabsf(x.y)), fmaxf(fabsf(x.z), fabsf(x.w))));
    }
#pragma unroll
    for (int m = 1; m < 64; m <<= 1) am = fmaxf(am, __shfl_xor(am, m));
    const _Float16 sh = (_Float16)(am / 127.0f);   // RTN to fp16, like astype(float16)
    const float s = (float)sh;
    if (lane == 0) smax[r0 + rl] = sh;
    signed char* row = qt + rl * 4096;
#pragma unroll
    for (int j = 0; j < 16; ++j) {
      float4 x = v[j];
      char4 c;
      c.x = (signed char)(x.x / s);      // fp32 divide + trunc = astype(int8)
      c.y = (signed char)(x.y / s);
      c.z = (signed char)(x.z / s);
      c.w = (signed char)(x.w / s);
      const int c2 = j * 16 + (lane >> 2);
      *(char4*)(row + ((c2 ^ rl) << 4) + (lane & 3) * 4) = c;   // 2-way max (free)
    }
  }
  __syncthreads();
  // store phase: 2048 int4, 128B-contiguous global segments
  const size_t pbase = (size_t)(r0 >> 5) * 32 * K + (size_t)(r0 & 31) * 16;
#pragma unroll
  for (int i = 0; i < 8; ++i) {
    const int s2 = i * 256 + t;
    const int c2 = s2 >> 3, rl = s2 & 7;
    int4 d = *(const int4*)(qt + rl * 4096 + ((c2 ^ rl) << 4));
    *(int4*)(q + pbase + (size_t)c2 * 512 + rl * 16) = d;
  }
  { // outlier gather: 32 idx x 8 rows
    const int j = t >> 3, rl = t & 7;
    unq[(size_t)j * R + r0 + rl] = src[(size_t)(r0 + rl) * K + idxg[j]];
  }
}

// ---------------- kernel D: i8 GEMM, 2-deep pipelined, fused epilogue ----------------
__device__ __forceinline__ void gld_lds16(const signed char* g, signed char* l) {
  __builtin_amdgcn_global_load_lds(
      (const __attribute__((address_space(1))) void*)g,
      (__attribute__((address_space(3))) void*)l, 16, 0, 0);
}

__global__ __launch_bounds__(256, 2) void gemm_kernel(
    const signed char* __restrict__ xq, const signed char* __restrict__ wq,
    const _Float16* __restrict__ xmax, const _Float16* __restrict__ wmax,
    const float* __restrict__ xuf,   // [ALPHA][M]
    const float* __restrict__ wuf,   // [ALPHA][N]
    const float* __restrict__ bias,  // [N]
    float* __restrict__ out, int M, int N, int K) {
  __shared__ union {
    struct { signed char A[3][BM * BK]; signed char B[3][BN * BK]; } g;  // 72 KB, 3-buf
    struct { float xu[ALPHA * BM]; float wu[ALPHA * BN]; } e;            // 48 KB
  } sm;
  __shared__ _Float16 xmh[BM];
  __shared__ _Float16 wmh[BN];
  __shared__ float    bl[BN];

  const int t = threadIdx.x;
  // XCD-aware swizzle: 1024 blocks, 8 XCDs -> each XCD owns 4 consecutive bx.
  const int bid = blockIdx.y * gridDim.x + blockIdx.x;
  const int xcd = bid & 7, loc = bid >> 3;
  const int bxi = xcd * 4 + (loc & 3);
  const int byi = loc >> 2;
  const int bm0 = byi * BM;
  const int bn0 = bxi * BN;
  const int lane = t & 63, w = t >> 6;
  const int wm = w >> 1, wn = w & 1;       // 2x2 waves, wave tile 128x64
  const int hi = lane >> 5, l31 = lane & 31;

  i32x16 acc[4][2] = {};

  const int tp = t >> 7;                  // panel parity within an issue
  const int to = (t & 127) * 16;
  const signed char* aS = xq + (size_t)bm0 * K + (size_t)tp * 32 * K + to;
  const signed char* bS = wq + (size_t)bn0 * K + (size_t)tp * 32 * K + to;
  signed char* const aD = &sm.g.A[0][0] + t * 16;
  signed char* const bD = &sm.g.B[0][0] + t * 16;
  const size_t PSTR = (size_t)64 * K;     // 2-panel stride

  auto STAGE = [&](int buf, int kt) {
    const size_t ko = (size_t)kt * 2048;  // (kt*64)>>4 * 512
#pragma unroll
    for (int i = 0; i < 4; ++i)
      gld_lds16(aS + (size_t)i * PSTR + ko, aD + buf * (BM * BK) + i * 4096);
#pragma unroll
    for (int i = 0; i < 2; ++i)
      gld_lds16(bS + (size_t)i * PSTR + ko, bD + buf * (BN * BK) + i * 4096);
  };

  const int NT = K >> 6;   // 64
  STAGE(0, 0);
  STAGE(1, 1);
  const signed char* const aR0 = &sm.g.A[0][0] + (wm * 4) * 2048 + 16 * lane;
  const signed char* const bR0 = &sm.g.B[0][0] + (wn * 2) * 2048 + 16 * lane;

  int cur = 0, st = 2;
  for (int kt = 0; kt < NT - 1; ++kt) {
    // tile kt's loads were issued 2 iters ago: counted wait, never drain to 0.
    asm volatile("s_waitcnt vmcnt(6)" ::: "memory");
    asm volatile("s_barrier" ::: "memory");
    const signed char* aRd = aR0 + cur * (BM * BK);
    const signed char* bRd = bR0 + cur * (BN * BK);
    i32x4 af[2][4], bf[2][2];
#pragma unroll
    for (int ks = 0; ks < 2; ++ks) {
#pragma unroll
      for (int mi = 0; mi < 4; ++mi) af[ks][mi] = *(const i32x4*)(aRd + mi * 2048 + ks * 1024);
#pragma unroll
      for (int ni = 0; ni < 2; ++ni) bf[ks][ni] = *(const i32x4*)(bRd + ni * 2048 + ks * 1024);
    }
    if (kt + 2 < NT) STAGE(st, kt + 2);   // 2-deep prefetch
    __builtin_amdgcn_s_setprio(1);
#pragma unroll
    for (int ks = 0; ks < 2; ++ks)
#pragma unroll
      for (int mi = 0; mi < 4; ++mi)
#pragma unroll
        for (int ni = 0; ni < 2; ++ni)
          acc[mi][ni] = __builtin_amdgcn_mfma_i32_32x32x32_i8(af[ks][mi], bf[ks][ni], acc[mi][ni], 0, 0, 0);
    __builtin_amdgcn_s_setprio(0);
    if (++cur == 3) cur = 0;
    if (++st == 3) st = 0;
  }
  { // peeled last tile: only here do we drain
    asm volatile("s_waitcnt vmcnt(0)" ::: "memory");
    asm volatile("s_barrier" ::: "memory");
    const signed char* aRd = aR0 + cur * (BM * BK);
    const signed char* bRd = bR0 + cur * (BN * BK);
    i32x4 af[2][4], bf[2][2];
#pragma unroll
    for (int ks = 0; ks < 2; ++ks) {
#pragma unroll
      for (int mi = 0; mi < 4; ++mi) af[ks][mi] = *(const i32x4*)(aRd + mi * 2048 + ks * 1024);
#pragma unroll
      for (int ni = 0; ni < 2; ++ni) bf[ks][ni] = *(const i32x4*)(bRd + ni * 2048 + ks * 1024);
    }
    __builtin_amdgcn_s_setprio(1);
#pragma unroll
    for (int ks = 0; ks < 2; ++ks)
#pragma unroll
      for (int mi = 0; mi < 4; ++mi)
#pragma unroll
        for (int ni = 0; ni < 2; ++ni)
          acc[mi][ni] = __builtin_amdgcn_mfma_i32_32x32x32_i8(af[ks][mi], bf[ks][ni], acc[mi][ni], 0, 0, 0);
    __builtin_amdgcn_s_setprio(0);
  }

  __syncthreads();
  // ---- epilogue staging (reuses GEMM LDS) ----
  {
    const float4* xs = (const float4*)xuf;
    float4* xl = (float4*)sm.e.xu;
#pragma unroll
    for (int i = 0; i < 8; ++i) {   // 2048 float4
      int p = i * 256 + t;
      int j = p >> 6, r4 = p & 63;
      xl[p] = xs[(size_t)j * (M >> 2) + (bm0 >> 2) + r4];
    }
    const float4* wsrc = (const float4*)wuf;
    float4* wl = (float4*)sm.e.wu;
#pragma unroll
    for (int i = 0; i < 4; ++i) {   // 1024 float4
      int p = i * 256 + t;
      int j = p >> 5, r4 = p & 31;
      wl[p] = wsrc[(size_t)j * (N >> 2) + (bn0 >> 2) + r4];
    }
    if (t < BM / 2) ((unsigned*)xmh)[t] = ((const unsigned*)(xmax + bm0))[t];
    if (t < BN / 2) ((unsigned*)wmh)[t] = ((const unsigned*)(wmax + bn0))[t];
    if (t < BN / 4) ((float4*)bl)[t] = ((const float4*)(bias + bn0))[t];
  }
  __syncthreads();

  const int c0 = wn * 64 + l31;   // column (within tile) for ni=0; ni=1 is +32
  const _Float16 wh0 = wmh[c0], wh1 = wmh[c0 + 32];
  const float bv0 = bl[c0], bv1 = bl[c0 + 32];
  const float* xul = sm.e.xu;     // [ALPHA][BM]
  const float* wul = sm.e.wu;     // [ALPHA][BN]

#pragma unroll
  for (int mi = 0; mi < 4; ++mi) {
    const int rbase = wm * 128 + mi * 32 + 4 * hi;   // + (r&3) + 8*(r>>2)
    float f0[16], f1[16];
#pragma unroll
    for (int r = 0; r < 16; ++r) {
      int row = rbase + (r & 3) + 8 * (r >> 2);
      _Float16 xh = xmh[row];
      float mx0 = (float)(_Float16)(xh * wh0);   // fp16 multiply (subnormal-correct) like ref
      float mx1 = (float)(_Float16)(xh * wh1);
      f0[r] = (float)acc[mi][0][r] * mx0 + bv0;
      f1[r] = (float)acc[mi][1][r] * mx1 + bv1;
    }
#pragma unroll 4
    for (int j = 0; j < ALPHA; ++j) {            // rank-32 fp32 outlier update
      const float4* xrow4 = (const float4*)(xul + j * BM + rbase);
      float wv0 = wul[j * BN + c0];
      float wv1 = wul[j * BN + c0 + 32];
#pragma unroll
      for (int gq = 0; gq < 4; ++gq) {
        float4 xv = xrow4[gq * 2];               // rows rbase + 8*gq .. +3
        f0[gq * 4 + 0] += xv.x * wv0;  f1[gq * 4 + 0] += xv.x * wv1;
        f0[gq * 4 + 1] += xv.y * wv0;  f1[gq * 4 + 1] += xv.y * wv1;
        f0[gq * 4 + 2] += xv.z * wv0;  f1[gq * 4 + 2] += xv.z * wv1;
        f0[gq * 4 + 3] += xv.w * wv0;  f1[gq * 4 + 3] += xv.w * wv1;
      }
    }
#pragma unroll
    for (int r = 0; r < 16; ++r) {
      int row = bm0 + rbase + (r & 3) + 8 * (r >> 2);
      size_t o = (size_t)row * N + bn0;
      out[o + c0] = f0[r];
      out[o + c0 + 32] = f1[r];
    }
  }
}

// ---------------- launch ----------------
extern "C" void kernel_launch(void* const* d_in, const int* in_sizes, int n_in,
                              void* d_out, int out_size, void* d_ws, size_t ws_size,
                              hipStream_t stream) {
  const float* x       = (const float*)d_in[0];
  const float* W       = (const float*)d_in[1];
  const float* bias    = (const float*)d_in[2];
  const float* act_max = (const float*)d_in[3];
  const int K = in_sizes[3];            // 4096
  const int N = in_sizes[1] / K;        // 4096
  const int M = in_sizes[0] / K;        // 8192
  float* out = (float*)d_out;

  char* ws = (char*)d_ws;
  size_t off = 0;
  auto take = [&](size_t b) { char* p = ws + off; off += (b + 255) & ~(size_t)255; return p; };
  signed char* wq  = (signed char*)take((size_t)N * K);
  signed char* xq  = (signed char*)take((size_t)M * K);
  _Float16* wmax   = (_Float16*)take((size_t)N * 2);
  _Float16* xmax   = (_Float16*)take((size_t)M * 2);
  float* wuf       = (float*)take((size_t)ALPHA * N * 4);
  float* xuf       = (float*)take((size_t)ALPHA * M * 4);
  int* idx         = (int*)take(ALPHA * 4);
  unsigned* tbits  = (unsigned*)take((size_t)(K / 32) * 4);

  const int nbw = N / 8, nbx = M / 8;   // 512 + 1024 = 1536 blocks
  topk_kernel<<<1, 256, 0, stream>>>(act_max, idx, tbits, K);
  quant8_kernel<<<nbw + nbx, 256, 0, stream>>>(W, x, tbits, idx, wq, xq,
                                               wmax, xmax, wuf, xuf, nbw, K, N, M);
  dim3 grid(N / BN, M / BM);
  gemm_kernel<<<grid, 256, 0, stream>>>(xq, wq, xmax, wmax, xuf, wuf, bias, out, M, N, K);
}

// Round 6
// 272.946 us; speedup vs baseline: 1.1564x; 1.0143x over previous
//
#include <hip/hip_runtime.h>
#include <hip/hip_fp16.h>

typedef __attribute__((ext_vector_type(4)))  int   i32x4;
typedef __attribute__((ext_vector_type(16))) int   i32x16;

#define ALPHA 32
#define BM 256
#define BN 256
#define BK 64

// Tiled int8 workspace layout (matches GEMM LDS exactly):
//   addr(row, k) = (row>>5)*(32*K) + (k>>4)*512 + (row&31)*16 + (k&15)

// ---------------- kernel A: top-32 of |act_max| + keep-bitmask ----------------
__global__ __launch_bounds__(256) void topk_kernel(const float* __restrict__ act_max,
                                                   int* __restrict__ idx_out,
                                                   unsigned* __restrict__ tbits,
                                                   int K) {
  __shared__ float v[4096];
  __shared__ float rv[4];
  __shared__ int   ri[4];
  __shared__ unsigned bits[128];
  const int t = threadIdx.x;
  for (int i = t; i < K; i += 256) v[i] = fabsf(act_max[i]);
  for (int i = t; i < K / 32; i += 256) bits[i] = 0xFFFFFFFFu;
  __syncthreads();
  for (int sel = 0; sel < ALPHA; ++sel) {
    float bv = -1.f; int bi = 0;
    for (int i = t; i < K; i += 256) {
      float x = v[i];
      if (x > bv) { bv = x; bi = i; }
    }
    for (int m = 1; m < 64; m <<= 1) {
      float ov = __shfl_xor(bv, m);
      int   oi = __shfl_xor(bi, m);
      if (ov > bv || (ov == bv && oi < bi)) { bv = ov; bi = oi; }
    }
    if ((t & 63) == 0) { rv[t >> 6] = bv; ri[t >> 6] = bi; }
    __syncthreads();
    if (t == 0) {
      for (int u = 1; u < 4; ++u)
        if (rv[u] > bv || (rv[u] == bv && ri[u] < bi)) { bv = rv[u]; bi = ri[u]; }
      idx_out[sel] = bi;
      v[bi] = -2.f;
      bits[bi >> 5] &= ~(1u << (bi & 31));
    }
    __syncthreads();
  }
  for (int i = t; i < K / 32; i += 256) tbits[i] = bits[i];
}

// ------------- kernel B: 8-rows-per-block quantization + gather -------------
__global__ __launch_bounds__(256) void quant8_kernel(
    const float* __restrict__ srcW, const float* __restrict__ srcX,
    const unsigned* __restrict__ tbits, const int* __restrict__ idxg,
    signed char* __restrict__ wq, signed char* __restrict__ xq,
    _Float16* __restrict__ wmax, _Float16* __restrict__ xmax,
    float* __restrict__ wuf, float* __restrict__ xuf,
    int nbw, int K, int N, int M) {
  const int t = threadIdx.x, lane = t & 63, w = t >> 6;
  const int b = blockIdx.x;
  const float* src; signed char* q; _Float16* smax; float* unq; int r0, R;
  if (b < nbw) { src = srcW; q = wq; smax = wmax; unq = wuf; r0 = b * 8; R = N; }
  else         { src = srcX; q = xq; smax = xmax; unq = xuf; r0 = (b - nbw) * 8; R = M; }
  __shared__ unsigned bits[128];
  __shared__ signed char qt[8 * 4096];   // [row][swizzled chunk]
  for (int i = t; i < 128; i += 256) bits[i] = tbits[i];
  __syncthreads();
  const int shft = (lane & 7) * 4;
#pragma unroll
  for (int g = 0; g < 2; ++g) {
    const int rl = w + 4 * g;            // local row 0..7
    const float4* srow = (const float4*)(src + (size_t)(r0 + rl) * K);
    float4 v[16];
    float am = 0.f;
#pragma unroll
    for (int j = 0; j < 16; ++j) {       // wave reads 1KB contiguous per instr
      float4 x = srow[j * 64 + lane];
      unsigned b4 = bits[j * 8 + (lane >> 3)] >> shft;
      if (!(b4 & 1u)) x.x = 0.f;
      if (!(b4 & 2u)) x.y = 0.f;
      if (!(b4 & 4u)) x.z = 0.f;
      if (!(b4 & 8u)) x.w = 0.f;
      v[j] = x;
      am = fmaxf(am, fmaxf(fmaxf(fabsf(x.x), fabsf(x.y)), fmaxf(fabsf(x.z), fabsf(x.w))));
    }
#pragma unroll
    for (int m = 1; m < 64; m <<= 1) am = fmaxf(am, __shfl_xor(am, m));
    const _Float16 sh = (_Float16)(am / 127.0f);   // RTN to fp16, like astype(float16)
    const float s = (float)sh;
    if (lane == 0) smax[r0 + rl] = sh;
    signed char* row = qt + rl * 4096;
#pragma unroll
    for (int j = 0; j < 16; ++j) {
      float4 x = v[j];
      char4 c;
      c.x = (signed char)(x.x / s);      // fp32 divide + trunc = astype(int8)
      c.y = (signed char)(x.y / s);
      c.z = (signed char)(x.z / s);
      c.w = (signed char)(x.w / s);
      const int c2 = j * 16 + (lane >> 2);
      *(char4*)(row + ((c2 ^ rl) << 4) + (lane & 3) * 4) = c;   // 2-way max (free)
    }
  }
  __syncthreads();
  // store phase: 2048 int4, 128B-contiguous global segments
  const size_t pbase = (size_t)(r0 >> 5) * 32 * K + (size_t)(r0 & 31) * 16;
#pragma unroll
  for (int i = 0; i < 8; ++i) {
    const int s2 = i * 256 + t;
    const int c2 = s2 >> 3, rl = s2 & 7;
    int4 d = *(const int4*)(qt + rl * 4096 + ((c2 ^ rl) << 4));
    *(int4*)(q + pbase + (size_t)c2 * 512 + rl * 16) = d;
  }
  { // outlier gather: 32 idx x 8 rows
    const int j = t >> 3, rl = t & 7;
    unq[(size_t)j * R + r0 + rl] = src[(size_t)(r0 + rl) * K + idxg[j]];
  }
}

// ---- kernel D: i8 GEMM, 256x256 tile, 8-wave, per-phase interleave (T3+T4+T5) ----
__device__ __forceinline__ void gld_lds16(const signed char* g, signed char* l) {
  __builtin_amdgcn_global_load_lds(
      (const __attribute__((address_space(1))) void*)g,
      (__attribute__((address_space(3))) void*)l, 16, 0, 0);
}

__global__ __launch_bounds__(512, 2) void gemm_kernel(
    const signed char* __restrict__ xq, const signed char* __restrict__ wq,
    const _Float16* __restrict__ xmax, const _Float16* __restrict__ wmax,
    const float* __restrict__ xuf,   // [ALPHA][M]
    const float* __restrict__ wuf,   // [ALPHA][N]
    const float* __restrict__ bias,  // [N]
    float* __restrict__ out, int M, int N, int K) {
  __shared__ union {
    struct { signed char A[4][BM * BK]; signed char B[4][BN * BK]; } g;  // 128 KB, 4-buf ring
    struct { float xu[ALPHA * BM]; float wu[ALPHA * BN];
             _Float16 xmh[BM]; _Float16 wmh[BN]; float bl[BN]; } e;      // 66 KB
  } sm;

  const int t = threadIdx.x;
  // XCD-aware swizzle: 512 blocks, 8 XCDs -> each XCD owns 2 bx columns (2MB B-panel in L2).
  const int bid = blockIdx.y * gridDim.x + blockIdx.x;
  const int xcd = bid & 7, loc = bid >> 3;
  const int bxi = xcd * 2 + (loc & 1);
  const int byi = loc >> 1;
  const int bm0 = byi * BM;
  const int bn0 = bxi * BN;
  const int lane = t & 63, w = t >> 6;
  const int wm = w >> 2, wn = w & 3;       // 2M x 4N waves, wave tile 128x64
  const int hi = lane >> 5, l31 = lane & 31;

  i32x16 acc[4][2] = {};

  // staging: issue covers 4 panels (t>>7) x 2KB (4 chunk-cols), contiguous per panel.
  const size_t P32 = (size_t)32 * K;
  const signed char* aS = xq + (size_t)bm0 * K + (size_t)(t >> 7) * P32 + (t & 127) * 16;
  const signed char* bS = wq + (size_t)bn0 * K + (size_t)(t >> 7) * P32 + (t & 127) * 16;
  signed char* const aD = &sm.g.A[0][0] + t * 16;
  signed char* const bD = &sm.g.B[0][0] + t * 16;

  auto STAGE_A = [&](int buf, int kt) {
    const size_t ko = (size_t)kt * 2048;
    gld_lds16(aS + ko, aD + buf * (BM * BK));
    gld_lds16(aS + ko + 4 * P32, aD + buf * (BM * BK) + 8192);
  };
  auto STAGE_B = [&](int buf, int kt) {
    const size_t ko = (size_t)kt * 2048;
    gld_lds16(bS + ko, bD + buf * (BN * BK));
    gld_lds16(bS + ko + 4 * P32, bD + buf * (BN * BK) + 8192);
  };

  const int NT = K >> 6;   // 64 K-tiles of 64
  // prologue: stage tiles 0,1,2 (12 issues), wait tile 0 (8 left in flight)
  STAGE_A(0, 0); STAGE_B(0, 0);
  STAGE_A(1, 1); STAGE_B(1, 1);
  STAGE_A(2, 2); STAGE_B(2, 2);
  asm volatile("s_waitcnt vmcnt(8)" ::: "memory");
  asm volatile("s_barrier" ::: "memory");

  // per-wave fragment read bases (lane-linear, conflict-free)
  const signed char* const aBase = &sm.g.A[0][0] + (wm * 4) * 2048 + hi * 512 + l31 * 16;
  const signed char* const bBase = &sm.g.B[0][0] + (wn * 2) * 2048 + hi * 512 + l31 * 16;

#define MFMA8()                                                                        \
  acc[0][0] = __builtin_amdgcn_mfma_i32_32x32x32_i8(a0, b0, acc[0][0], 0, 0, 0);       \
  acc[0][1] = __builtin_amdgcn_mfma_i32_32x32x32_i8(a0, b1, acc[0][1], 0, 0, 0);       \
  acc[1][0] = __builtin_amdgcn_mfma_i32_32x32x32_i8(a1, b0, acc[1][0], 0, 0, 0);       \
  acc[1][1] = __builtin_amdgcn_mfma_i32_32x32x32_i8(a1, b1, acc[1][1], 0, 0, 0);       \
  acc[2][0] = __builtin_amdgcn_mfma_i32_32x32x32_i8(a2, b0, acc[2][0], 0, 0, 0);       \
  acc[2][1] = __builtin_amdgcn_mfma_i32_32x32x32_i8(a2, b1, acc[2][1], 0, 0, 0);       \
  acc[3][0] = __builtin_amdgcn_mfma_i32_32x32x32_i8(a3, b0, acc[3][0], 0, 0, 0);       \
  acc[3][1] = __builtin_amdgcn_mfma_i32_32x32x32_i8(a3, b1, acc[3][1], 0, 0, 0)

#define ITERATION(DOSTAGE, WSTR)                                                       \
  {                                                                                    \
    const signed char* aRd = aBase + cur * (BM * BK);                                  \
    const signed char* bRd = bBase + cur * (BN * BK);                                  \
    /* ---- phase 0: slice 0 ---- */                                                   \
    i32x4 a0 = *(const i32x4*)(aRd + 0);                                               \
    i32x4 a1 = *(const i32x4*)(aRd + 2048);                                            \
    i32x4 a2 = *(const i32x4*)(aRd + 4096);                                            \
    i32x4 a3 = *(const i32x4*)(aRd + 6144);                                            \
    i32x4 b0 = *(const i32x4*)(bRd + 0);                                               \
    i32x4 b1 = *(const i32x4*)(bRd + 2048);                                            \
    if (DOSTAGE) STAGE_A((kt + 3) & 3, kt + 3);                                        \
    asm volatile("s_barrier" ::: "memory");                                            \
    asm volatile("s_waitcnt lgkmcnt(0)" ::: "memory");                                 \
    __builtin_amdgcn_sched_barrier(0);                                                 \
    __builtin_amdgcn_s_setprio(1);                                                     \
    MFMA8();                                                                           \
    __builtin_amdgcn_s_setprio(0);                                                     \
    asm volatile("s_barrier" ::: "memory");                                            \
    /* ---- phase 1: slice 1 ---- */                                                   \
    a0 = *(const i32x4*)(aRd + 1024);                                                  \
    a1 = *(const i32x4*)(aRd + 3072);                                                  \
    a2 = *(const i32x4*)(aRd + 5120);                                                  \
    a3 = *(const i32x4*)(aRd + 7168);                                                  \
    b0 = *(const i32x4*)(bRd + 1024);                                                  \
    b1 = *(const i32x4*)(bRd + 3072);                                                  \
    if (DOSTAGE) STAGE_B((kt + 3) & 3, kt + 3);                                        \
    asm volatile(WSTR ::: "memory");                                                   \
    asm volatile("s_barrier" ::: "memory");                                            \
    asm volatile("s_waitcnt lgkmcnt(0)" ::: "memory");                                 \
    __builtin_amdgcn_sched_barrier(0);                                                 \
    __builtin_amdgcn_s_setprio(1);                                                     \
    MFMA8();                                                                           \
    __builtin_amdgcn_s_setprio(0);                                                     \
    asm volatile("s_barrier" ::: "memory");                                            \
    cur = (cur + 1) & 3;                                                               \
  }

  int cur = 0;
  int kt = 0;
  for (; kt < NT - 3; ++kt) ITERATION(true, "s_waitcnt vmcnt(8)");
  ITERATION(false, "s_waitcnt vmcnt(4)"); ++kt;
  ITERATION(false, "s_waitcnt vmcnt(0)"); ++kt;
  ITERATION(false, "s_waitcnt vmcnt(0)");
#undef ITERATION
#undef MFMA8

  __syncthreads();
  // ---- epilogue staging (reuses GEMM LDS) ----
  {
    const float4* xs = (const float4*)xuf;
    float4* xl = (float4*)sm.e.xu;
#pragma unroll
    for (int i = 0; i < 4; ++i) {   // 2048 float4
      int p = i * 512 + t;
      int j = p >> 6, r4 = p & 63;
      xl[p] = xs[(size_t)j * (M >> 2) + (bm0 >> 2) + r4];
    }
    const float4* wsrc = (const float4*)wuf;
    float4* wl = (float4*)sm.e.wu;
#pragma unroll
    for (int i = 0; i < 4; ++i) {   // 2048 float4
      int p = i * 512 + t;
      int j = p >> 6, r4 = p & 63;
      wl[p] = wsrc[(size_t)j * (N >> 2) + (bn0 >> 2) + r4];
    }
    if (t < BM / 2) ((unsigned*)sm.e.xmh)[t] = ((const unsigned*)(xmax + bm0))[t];
    if (t < BN / 2) ((unsigned*)sm.e.wmh)[t] = ((const unsigned*)(wmax + bn0))[t];
    if (t < BN / 4) ((float4*)sm.e.bl)[t] = ((const float4*)(bias + bn0))[t];
  }
  __syncthreads();

  const int c0 = wn * 64 + l31;   // column (within tile) for ni=0; ni=1 is +32
  const _Float16 wh0 = sm.e.wmh[c0], wh1 = sm.e.wmh[c0 + 32];
  const float bv0 = sm.e.bl[c0], bv1 = sm.e.bl[c0 + 32];
  const float* xul = sm.e.xu;     // [ALPHA][BM]
  const float* wul = sm.e.wu;     // [ALPHA][BN]

#pragma unroll
  for (int mi = 0; mi < 4; ++mi) {
    const int rbase = wm * 128 + mi * 32 + 4 * hi;   // + (r&3) + 8*(r>>2)
    float f0[16], f1[16];
#pragma unroll
    for (int r = 0; r < 16; ++r) {
      int row = rbase + (r & 3) + 8 * (r >> 2);
      _Float16 xh = sm.e.xmh[row];
      float mx0 = (float)(_Float16)(xh * wh0);   // fp16 multiply (subnormal-correct) like ref
      float mx1 = (float)(_Float16)(xh * wh1);
      f0[r] = (float)acc[mi][0][r] * mx0 + bv0;
      f1[r] = (float)acc[mi][1][r] * mx1 + bv1;
    }
#pragma unroll 4
    for (int j = 0; j < ALPHA; ++j) {            // rank-32 fp32 outlier update
      const float4* xrow4 = (const float4*)(xul + j * BM + rbase);
      float wv0 = wul[j * BN + c0];
      float wv1 = wul[j * BN + c0 + 32];
#pragma unroll
      for (int gq = 0; gq < 4; ++gq) {
        float4 xv = xrow4[gq * 2];               // rows rbase + 8*gq .. +3
        f0[gq * 4 + 0] += xv.x * wv0;  f1[gq * 4 + 0] += xv.x * wv1;
        f0[gq * 4 + 1] += xv.y * wv0;  f1[gq * 4 + 1] += xv.y * wv1;
        f0[gq * 4 + 2] += xv.z * wv0;  f1[gq * 4 + 2] += xv.z * wv1;
        f0[gq * 4 + 3] += xv.w * wv0;  f1[gq * 4 + 3] += xv.w * wv1;
      }
    }
#pragma unroll
    for (int r = 0; r < 16; ++r) {
      int row = bm0 + rbase + (r & 3) + 8 * (r >> 2);
      size_t o = (size_t)row * N + bn0;
      out[o + c0] = f0[r];
      out[o + c0 + 32] = f1[r];
    }
  }
}

// ---------------- launch ----------------
extern "C" void kernel_launch(void* const* d_in, const int* in_sizes, int n_in,
                              void* d_out, int out_size, void* d_ws, size_t ws_size,
                              hipStream_t stream) {
  const float* x       = (const float*)d_in[0];
  const float* W       = (const float*)d_in[1];
  const float* bias    = (const float*)d_in[2];
  const float* act_max = (const float*)d_in[3];
  const int K = in_sizes[3];            // 4096
  const int N = in_sizes[1] / K;        // 4096
  const int M = in_sizes[0] / K;        // 8192
  float* out = (float*)d_out;

  char* ws = (char*)d_ws;
  size_t off = 0;
  auto take = [&](size_t b) { char* p = ws + off; off += (b + 255) & ~(size_t)255; return p; };
  signed char* wq  = (signed char*)take((size_t)N * K);
  signed char* xq  = (signed char*)take((size_t)M * K);
  _Float16* wmax   = (_Float16*)take((size_t)N * 2);
  _Float16* xmax   = (_Float16*)take((size_t)M * 2);
  float* wuf       = (float*)take((size_t)ALPHA * N * 4);
  float* xuf       = (float*)take((size_t)ALPHA * M * 4);
  int* idx         = (int*)take(ALPHA * 4);
  unsigned* tbits  = (unsigned*)take((size_t)(K / 32) * 4);

  const int nbw = N / 8, nbx = M / 8;   // 512 + 1024 = 1536 blocks
  topk_kernel<<<1, 256, 0, stream>>>(act_max, idx, tbits, K);
  quant8_kernel<<<nbw + nbx, 256, 0, stream>>>(W, x, tbits, idx, wq, xq,
                                               wmax, xmax, wuf, xuf, nbw, K, N, M);
  dim3 grid(N / BN, M / BM);
  gemm_kernel<<<grid, 512, 0, stream>>>(xq, wq, xmax, wmax, xuf, wuf, bias, out, M, N, K);
}